// Round 5
// baseline (247.464 us; speedup 1.0000x reference)
//
#include <hip/hip_runtime.h>
#include <hip/hip_bf16.h>

typedef __bf16 bf16;
typedef __bf16 bf16x2 __attribute__((ext_vector_type(2)));
typedef __bf16 bf16x8 __attribute__((ext_vector_type(8)));
typedef float f32x4 __attribute__((ext_vector_type(4)));
typedef float f32x16 __attribute__((ext_vector_type(16)));

#define MFMA16(a, b, c) __builtin_amdgcn_mfma_f32_16x16x32_bf16(a, b, c, 0, 0, 0)
#define MFMA32(a, b, c) __builtin_amdgcn_mfma_f32_32x32x16_bf16(a, b, c, 0, 0, 0)

// 0.125 (1/sqrt(DK)) * log2(e): folded into Q projection so attention uses exp2.
#define QSCALE 0.18033688f

// Async global->LDS, 16B per lane. Dest must be wave-uniform base (+lane*16).
__device__ __forceinline__ void gld16(const bf16* g, bf16* l) {
  __builtin_amdgcn_global_load_lds(
      (const __attribute__((address_space(1))) void*)g,
      (__attribute__((address_space(3))) void*)l, 16, 0, 0);
}

// ---------------------------------------------------------------------------
// Transpose + f32->bf16 convert the four weight matrices [1024,1024].
// Wt[n][k] = W[k][n].  grid (16,16,4), block 256.
// ---------------------------------------------------------------------------
__global__ __launch_bounds__(256) void transpose_w(const float* __restrict__ w0,
                                                   const float* __restrict__ w1,
                                                   const float* __restrict__ w2,
                                                   const float* __restrict__ w3,
                                                   bf16* __restrict__ dst) {
  __shared__ bf16 T[64][68];
  const float* W = blockIdx.z == 0 ? w0 : blockIdx.z == 1 ? w1
                   : blockIdx.z == 2 ? w2 : w3;
  bf16* Y = dst + (size_t)blockIdx.z * 1024 * 1024;
  const int t = threadIdx.x, r = t >> 2, c4 = t & 3;
  const int k0 = blockIdx.y * 64, n0 = blockIdx.x * 64;

  const float4* src = (const float4*)(W + (size_t)(k0 + r) * 1024 + n0 + c4 * 16);
  float4 f0 = src[0], f1 = src[1], f2 = src[2], f3 = src[3];
  bf16* row = &T[r][c4 * 16];
  row[0] = (bf16)f0.x; row[1] = (bf16)f0.y; row[2] = (bf16)f0.z; row[3] = (bf16)f0.w;
  row[4] = (bf16)f1.x; row[5] = (bf16)f1.y; row[6] = (bf16)f1.z; row[7] = (bf16)f1.w;
  row[8] = (bf16)f2.x; row[9] = (bf16)f2.y; row[10] = (bf16)f2.z; row[11] = (bf16)f2.w;
  row[12] = (bf16)f3.x; row[13] = (bf16)f3.y; row[14] = (bf16)f3.z; row[15] = (bf16)f3.w;
  __syncthreads();

  bf16x8 o0, o1;
#pragma unroll
  for (int j = 0; j < 8; ++j) o0[j] = T[c4 * 16 + j][r];
#pragma unroll
  for (int j = 0; j < 8; ++j) o1[j] = T[c4 * 16 + 8 + j][r];
  bf16* d = Y + (size_t)(n0 + r) * 1024 + k0 + c4 * 16;
  *(bf16x8*)d = o0;
  *(bf16x8*)(d + 8) = o1;
}

// ---------------------------------------------------------------------------
// GEMM v3: (MT*32)x128 tile, BK=64.
// LDS layout LINEAR [rows][64] bf16 (128 B/row) with XOR chunk swizzle:
//   16B chunk c of row r lives at byte r*128 + 16*(c ^ (r&7)).
// B operand: m97-style global_load_lds staging (linear DMA dest +
//   inverse-swizzled GLOBAL source) -- unchanged from round-4-verified v2.
// A operand:
//   QKV=1 (MT=4): staged directly from the f32 inputs q/k/v with
//     in-register f32->bf16 convert + swizzled ds_write_b128 (this fuses
//     the former convert_k kernel into the GEMM). Next step's f32 loads
//     issue after the 2nd barrier -> latency hides under MFMA.
//   QKV=0 (MT=2): bf16 input (attn out), gld16 like B.
// Fragment reads identical in both paths (same swizzled layout).
// z=0: Q -> Qp [B,H,S,DK] scaled; z=1: K -> Kp; z=2: V -> Vtp [B,H,DK,S]
//   via in-LDS transpose (Tt spans SH; same-type aliasing, barrier-fenced).
// QKV=0: O projection -> Yf row-major f32.
// ---------------------------------------------------------------------------
template <int QKV, int MT>
__global__ __launch_bounds__(256, 3) void gemm_p(
    const float* __restrict__ xq, const float* __restrict__ xk,
    const float* __restrict__ xv, const bf16* __restrict__ xo,
    const bf16* __restrict__ Wt, const float* __restrict__ bq,
    const float* __restrict__ bk, const float* __restrict__ bv,
    bf16* __restrict__ Qp, bf16* __restrict__ Kp, bf16* __restrict__ Vtp,
    float* __restrict__ Yf) {
  constexpr int AROWS = MT * 32;
  __shared__ __align__(16) bf16 SH[AROWS * 64 + 128 * 64];
  bf16* Al = SH;
  bf16* Bl = SH + AROWS * 64;

  const int z = QKV ? blockIdx.z : 0;
  const float* Xf = QKV ? (z == 0 ? xq : z == 1 ? xk : xv) : nullptr;
  const bf16* Bt = Wt + (size_t)z * 1048576;
  const float* bias = QKV ? (z == 0 ? bq : z == 1 ? bk : bv) : bq;
  const float escale = (QKV && z == 0) ? QSCALE : 1.0f;

  const int t = threadIdx.x;
  const int wave = t >> 6, lane = t & 63, quad = lane >> 4, l16 = lane & 15;
  const int wm = (wave >> 1) * (MT * 16), wn = (wave & 1) * 64;
  const int bm = blockIdx.y * AROWS, bn = blockIdx.x * 128;

  // ---- B staging (gld16): lane -> (row-in-chunk lr, dest chunk lc);
  //      global chunk = lc^lr (rule-21 inverse swizzle)
  const int lr = (lane >> 3) & 7, lc = lane & 7;
  const bf16* gB[4];
  bf16* lB[4];
#pragma unroll
  for (int i = 0; i < 4; ++i) {
    const int q = wave * 4 + i;  // 1KB chunk = 8 rows
    gB[i] = Bt + (size_t)(bn + 8 * q + lr) * 1024 + 8 * (lc ^ lr);
    lB[i] = Bl + q * 512;
  }

  // ---- A staging
  // QKV=1: f32 source, reg-staged. thread t -> row arow=t>>1, half=t&1
  //        covers bf16 cols [half*32, half*32+32) as 4 swizzled 16B chunks.
  const int arow = t >> 1, ahalf = t & 1;
  const float* gAf =
      QKV ? (Xf + (size_t)(bm + arow) * 1024 + ahalf * 32) : nullptr;
  bf16* aw[4];
#pragma unroll
  for (int j = 0; j < 4; ++j)
    aw[j] = (bf16*)((char*)Al + arow * 128 +
                    (((ahalf * 4 + j) ^ (arow & 7)) << 4));
  // QKV=0: bf16 source via gld16 (NAC = AROWS/32 = 2 chunks per wave)
  constexpr int NAC = AROWS / 32;
  const bf16* gA[NAC];
  bf16* lA[NAC];
#pragma unroll
  for (int i = 0; i < NAC; ++i) {
    const int q = wave * NAC + i;
    gA[i] = (QKV ? (const bf16*)nullptr
                 : xo + (size_t)(bm + 8 * q + lr) * 1024 + 8 * (lc ^ lr));
    lA[i] = Al + q * 512;
  }

  f32x4 acc[MT][4] = {};
  const int fswz = (l16 & 7) << 4;

  float4 rA[8];
  if constexpr (QKV) {
#pragma unroll
    for (int j = 0; j < 4; ++j) {
      rA[2 * j] = *(const float4*)(gAf + 8 * j);
      rA[2 * j + 1] = *(const float4*)(gAf + 8 * j + 4);
    }
  }

  for (int kb = 0; kb < 1024; kb += 64) {
    __syncthreads();  // all waves done reading previous tile
    if constexpr (QKV) {
#pragma unroll
      for (int j = 0; j < 4; ++j) {
        bf16x8 o;
        o[0] = (bf16)rA[2 * j].x; o[1] = (bf16)rA[2 * j].y;
        o[2] = (bf16)rA[2 * j].z; o[3] = (bf16)rA[2 * j].w;
        o[4] = (bf16)rA[2 * j + 1].x; o[5] = (bf16)rA[2 * j + 1].y;
        o[6] = (bf16)rA[2 * j + 1].z; o[7] = (bf16)rA[2 * j + 1].w;
        *(bf16x8*)aw[j] = o;
      }
    } else {
#pragma unroll
      for (int i = 0; i < NAC; ++i) gld16(gA[i] + kb, lA[i]);
    }
#pragma unroll
    for (int i = 0; i < 4; ++i) gld16(gB[i] + kb, lB[i]);
    __syncthreads();  // lgkm + vmcnt drain inserted by compiler

    if constexpr (QKV) {
      if (kb + 64 < 1024) {  // next A tile; lands during MFMA below
#pragma unroll
        for (int j = 0; j < 4; ++j) {
          rA[2 * j] = *(const float4*)(gAf + kb + 64 + 8 * j);
          rA[2 * j + 1] = *(const float4*)(gAf + kb + 64 + 8 * j + 4);
        }
      }
    }

#pragma unroll
    for (int kk = 0; kk < 2; ++kk) {
      const int cb = (kk * 64 + quad * 16) ^ fswz;
      bf16x8 af[MT], bfr[4];
#pragma unroll
      for (int mt = 0; mt < MT; ++mt)
        af[mt] = *(const bf16x8*)((const char*)Al +
                                  (wm + mt * 16 + l16) * 128 + cb);
#pragma unroll
      for (int nt = 0; nt < 4; ++nt)
        bfr[nt] = *(const bf16x8*)((const char*)Bl +
                                   (wn + nt * 16 + l16) * 128 + cb);
#pragma unroll
      for (int mt = 0; mt < MT; ++mt)
#pragma unroll
        for (int nt = 0; nt < 4; ++nt)
          acc[mt][nt] = MFMA16(af[mt], bfr[nt], acc[mt][nt]);
    }
  }

  if (QKV && z == 2) {
    // ---- V^T epilogue: in-LDS transpose (Tt spans SH), coalesced stores
    bf16* Tt = SH;  // 64*136 = 8704 elems <= 16384
    const int b = bm >> 11;
    __syncthreads();  // everyone done with Al/Bl before reuse
#pragma unroll
    for (int half = 0; half < 2; ++half) {
      if ((wave & 1) == half) {
#pragma unroll
        for (int nt = 0; nt < 4; ++nt) {
          const int ln = nt * 16 + l16;
          const float bia = bias[bn + half * 64 + ln];
#pragma unroll
          for (int mt = 0; mt < 4; ++mt)
#pragma unroll
            for (int r = 0; r < 4; ++r) {
              const int m = wm + mt * 16 + quad * 4 + r;
              Tt[ln * 136 + m] = (bf16)(acc[mt][nt][r] + bia);
            }
        }
      }
      __syncthreads();
      {
        const int ln = t >> 2, seg = (t & 3) * 32;
        const int gn = bn + half * 64 + ln;
        const int h = gn >> 6, dk = gn & 63;
        const int s0 = (bm & 2047) + seg;
        bf16* dstp = Vtp + ((size_t)(b * 16 + h) * 64 + dk) * 2048 + s0;
        const bf16* srcp = Tt + ln * 136 + seg;
#pragma unroll
        for (int j = 0; j < 4; ++j)
          *(bf16x8*)(dstp + j * 8) = *(const bf16x8*)(srcp + j * 8);
      }
      __syncthreads();
    }
  } else {
    // ---- regular epilogue. C/D layout: row = quad*4 + r, col = l16 ----
#pragma unroll
    for (int mt = 0; mt < MT; ++mt)
#pragma unroll
      for (int nt = 0; nt < 4; ++nt) {
        const int gn = bn + wn + nt * 16 + l16;
        const float bia = bias[gn];
#pragma unroll
        for (int r = 0; r < 4; ++r) {
          const int gm = bm + wm + mt * 16 + quad * 4 + r;
          const float val = (acc[mt][nt][r] + bia) * escale;
          if (!QKV) {
            Yf[(size_t)gm * 1024 + gn] = val;
          } else {
            const int b = gm >> 11, s = gm & 2047;  // S = 2048
            const int h = gn >> 6, dk = gn & 63;    // DK = 64
            bf16* Y = (z == 0) ? Qp : Kp;
            Y[((size_t)(b * 16 + h) * 2048 + s) * 64 + dk] = (bf16)val;
          }
        }
      }
  }
}

// ---------------------------------------------------------------------------
// Flash attention v3b: causal, no-running-max, 32x32x16 MFMA, swapped QK^T,
// softmax in registers, P->A-frags via __shfl_xor (round-1-verified form).
//
// Parallel decomposition (tile-latency-bound => minimize tiles on critical
// wave with exact wave-level balance):
//   Block = 4 waves: wave w = (qsub = w&1  -> 32 q-rows,
//                              kpart = w>>1 -> even/odd 64-key tiles).
//   Two phases per block: q-tiles {x, 31-x} (64 rows each) -> every block
//   runs exactly 17 supersteps; every wave computes 16-17 key-tiles.
//   Partial (o, rs) combined across kpart at phase end via dedicated LDS
//   buffers (two rounds: o0+rs, then o1) -- exact, since no-running-max
//   softmax is linear in the partials.
// Grid 512: n -> xcd=n&7, bh=xcd+8*(mm&3), pairx=mm>>2 (K/V L2-resident/XCD).
//
// Superstep s stages tiles {2s, 2s+1} (K and V) double-buffered: 64 KB LDS,
// XOR-swizzled 16B chunks (byte ^= (row&7)<<4) on both write and read.
// One __syncthreads per superstep. LDS total 73 KB -> 2 blocks/CU.
// ---------------------------------------------------------------------------
__global__ __launch_bounds__(256, 2) void attn_k(const bf16* __restrict__ Q,
                                                 const bf16* __restrict__ K,
                                                 const bf16* __restrict__ Vt,
                                                 bf16* __restrict__ X) {
  __shared__ __align__(16) char LB[65536];  // KB[4][8KB] | VB[4][8KB]
  __shared__ float Ex[2048];   // 8 KB o-exchange (one f32x16 round at a time)
  __shared__ float ExR[128];   // rs exchange
  __shared__ float rsL[4][32];

  bf16* KB = (bf16*)LB;            // 4 K tiles (2 parity x 2 kpart)
  bf16* VB = (bf16*)(LB + 32768);  // 4 V tiles

  const int t = threadIdx.x;
  const int wave = t >> 6, lane = t & 63;
  const int cl = lane & 31, h = lane >> 5;
  const int qsub = wave & 1, kpart = wave >> 1;

  const int n = blockIdx.x;
  const int xcd = n & 7, mm = n >> 3;
  const int bh = xcd + 8 * (mm & 3);
  const int pairx = mm >> 2;
  const int b = bh >> 4, hh = bh & 15;

  const bf16* Qb = Q + (size_t)bh * 2048 * 64;
  const bf16* Kb = K + (size_t)bh * 2048 * 64;
  const bf16* Vb = Vt + (size_t)bh * 64 * 2048;

  // staging role: thread t covers row sr, two swizzled 16B chunks
  const int sr = t >> 2, sc4 = t & 3;
  const int swz = (sr & 7) << 4;
  const int d0 = sr * 128 + ((sc4 * 32) ^ swz);
  const int d1 = sr * 128 + ((sc4 * 32 + 16) ^ swz);
  const int fswz = (cl & 7) << 4;  // frag-read swizzle (rows cl, cl+32)

  for (int ph = 0; ph < 2; ++ph) {
    const int qt = ph ? 31 - pairx : pairx;
    const int ntiles = qt + 1;
    const int S = (ntiles + 1) >> 1;  // supersteps (2 tiles each)
    const int q0 = qt * 64 + qsub * 32;

    // Q B-fragments (col = q = cl, k = d), kept in registers for the phase.
    bf16x8 qf[4];
#pragma unroll
    for (int ks = 0; ks < 4; ++ks)
      qf[ks] = *(const bf16x8*)(Qb + (size_t)(q0 + cl) * 64 + ks * 16 + h * 8);

    f32x16 o0 = {}, o1 = {};
    float rs = 0.f;

    // prologue: stage tiles {0,1} into parity-0 slots
#pragma unroll
    for (int p = 0; p < 2; ++p) {
      const bf16* gk = Kb + (size_t)(p * 64 + sr) * 64 + sc4 * 16;
      const bf16* gv = Vb + (size_t)sr * 2048 + p * 64 + sc4 * 16;
      bf16x8 ka = *(const bf16x8*)gk, kb2 = *(const bf16x8*)(gk + 8);
      bf16x8 va = *(const bf16x8*)gv, vb2 = *(const bf16x8*)(gv + 8);
      char* Kd = (char*)(KB + p * 4096);
      char* Vd = (char*)(VB + p * 4096);
      *(bf16x8*)(Kd + d0) = ka;  *(bf16x8*)(Kd + d1) = kb2;
      *(bf16x8*)(Vd + d0) = va;  *(bf16x8*)(Vd + d1) = vb2;
    }
    __syncthreads();

    for (int ss = 0; ss < S; ++ss) {
      const int par = ss & 1;
      const bool more = (ss + 1) < S;
      bf16x8 rk[2][2], rv[2][2];
      if (more) {  // prefetch both next-superstep tiles into registers
#pragma unroll
        for (int p = 0; p < 2; ++p) {
          const int kt2 = 2 * (ss + 1) + p;
          const bf16* gk = Kb + (size_t)kt2 * 4096 + sr * 64 + sc4 * 16;
          const bf16* gv = Vb + (size_t)sr * 2048 + kt2 * 64 + sc4 * 16;
          rk[p][0] = *(const bf16x8*)gk;
          rk[p][1] = *(const bf16x8*)(gk + 8);
          rv[p][0] = *(const bf16x8*)gv;
          rv[p][1] = *(const bf16x8*)(gv + 8);
        }
      }

      const int kt = 2 * ss + kpart;
      if (kt < ntiles) {
        const int k0 = kt * 64;
        const char* Kc = (const char*)(KB + (par * 2 + kpart) * 4096);
        const char* Vc = (const char*)(VB + (par * 2 + kpart) * 4096);
        const bool interior = (k0 + 63) <= q0;  // wave-uniform

        // ---- QK^T (swapped): S^T[key][q]
        f32x16 s0v = {}, s1v = {};
#pragma unroll
        for (int ks = 0; ks < 4; ++ks) {
          const int cb = ks * 32 + h * 16;
          bf16x8 f0 = *(const bf16x8*)(Kc + cl * 128 + (cb ^ fswz));
          bf16x8 f1 = *(const bf16x8*)(Kc + (cl + 32) * 128 + (cb ^ fswz));
          s0v = MFMA32(f0, qf[ks], s0v);
          s1v = MFMA32(f1, qf[ks], s1v);
        }

        // ---- softmax in registers: exp2, causal mask, row-sum, pack bf16
        unsigned pk[8][2];  // [s64 = key>>3][pair]
        float ts = 0.f;
        auto smax = [&](const f32x16& sv, int mk) {
#pragma unroll
          for (int sl = 0; sl < 4; ++sl)
#pragma unroll
            for (int p = 0; p < 2; ++p) {
              float e0 = exp2f(sv[sl * 4 + 2 * p]);
              float e1 = exp2f(sv[sl * 4 + 2 * p + 1]);
              if (!interior) {
                const int ky = k0 + mk * 32 + 8 * sl + 4 * h + 2 * p;
                const int qg = q0 + cl;
                if (ky > qg) e0 = 0.f;
                if (ky + 1 > qg) e1 = 0.f;
              }
              ts += e0 + e1;
              union { bf16x2 v; unsigned u; } cv;
              cv.v[0] = (bf16)e0;
              cv.v[1] = (bf16)e1;
              pk[mk * 4 + sl][p] = cv.u;
            }
        };
        smax(s0v, 0);
        smax(s1v, 1);
        rs += ts;

        // ---- P -> A-frags (round-1-verified shfl form):
        // lane (q=cl, h) frag ks elem j = P[q][16ks+8h+j]
        bf16x8 pf[4];
#pragma unroll
        for (int ks = 0; ks < 4; ++ks) {
          const unsigned oe0 = pk[2 * ks][0], oe1 = pk[2 * ks][1];
          const unsigned oo0 = pk[2 * ks + 1][0], oo1 = pk[2 * ks + 1][1];
          const unsigned pe0 = (unsigned)__shfl_xor((int)oe0, 32, 64);
          const unsigned pe1 = (unsigned)__shfl_xor((int)oe1, 32, 64);
          const unsigned po0 = (unsigned)__shfl_xor((int)oo0, 32, 64);
          const unsigned po1 = (unsigned)__shfl_xor((int)oo1, 32, 64);
          union { unsigned u[4]; bf16x8 v; } fu;
          fu.u[0] = h ? po0 : oe0;
          fu.u[1] = h ? po1 : oe1;
          fu.u[2] = h ? oo0 : pe0;
          fu.u[3] = h ? oo1 : pe1;
          pf[ks] = fu.v;
        }

        // ---- PV: O[q][d] += P[q][key] * V[key][d] (Vl rows = d)
#pragma unroll
        for (int ks = 0; ks < 4; ++ks) {
          const int cb = ks * 32 + h * 16;
          bf16x8 v0f = *(const bf16x8*)(Vc + cl * 128 + (cb ^ fswz));
          bf16x8 v1f = *(const bf16x8*)(Vc + (cl + 32) * 128 + (cb ^ fswz));
          o0 = MFMA32(pf[ks], v0f, o0);
          o1 = MFMA32(pf[ks], v1f, o1);
        }
      }

      if (more) {  // write prefetched tiles into the other parity slots
#pragma unroll
        for (int p = 0; p < 2; ++p) {
          char* Kd = (char*)(KB + ((par ^ 1) * 2 + p) * 4096);
          char* Vd = (char*)(VB + ((par ^ 1) * 2 + p) * 4096);
          *(bf16x8*)(Kd + d0) = rk[p][0];
          *(bf16x8*)(Kd + d1) = rk[p][1];
          *(bf16x8*)(Vd + d0) = rv[p][0];
          *(bf16x8*)(Vd + d1) = rv[p][1];
        }
      }
      __syncthreads();
    }

    // ---- combine partials across key partitions (exact: linear softmax)
    // Round A: o0 + rs
    if (kpart == 0) {
      float* e = Ex + qsub * 1024;
#pragma unroll
      for (int i = 0; i < 16; ++i) e[i * 64 + lane] = o0[i];
      ExR[qsub * 64 + lane] = rs;
    }
    __syncthreads();
    if (kpart == 1) {
      const float* e = Ex + qsub * 1024;
#pragma unroll
      for (int i = 0; i < 16; ++i) o0[i] += e[i * 64 + lane];
      rs += ExR[qsub * 64 + lane];
    }
    __syncthreads();
    // Round B: o1
    if (kpart == 0) {
      float* e = Ex + qsub * 1024;
#pragma unroll
      for (int i = 0; i < 16; ++i) e[i * 64 + lane] = o1[i];
    }
    __syncthreads();
    if (kpart == 1) {
      const float* e = Ex + qsub * 1024;
#pragma unroll
      for (int i = 0; i < 16; ++i) o1[i] += e[i * 64 + lane];

      // ---- epilogue: rinv broadcast via per-wave LDS, normalize, store
      const float rtot = rs + __shfl_xor(rs, 32, 64);
      rsL[wave][cl] = 1.0f / rtot;  // lanes h=0/1 write identical value
      __builtin_amdgcn_s_waitcnt(0xC07F);  // lgkmcnt(0): wave-local table
      bf16* Xb = X + (size_t)b * 2048 * 1024 + hh * 64;
#pragma unroll
      for (int g = 0; g < 16; ++g) {
        const int qr = (g & 3) + 8 * (g >> 2) + 4 * h;
        const float ri = rsL[wave][qr];
        const int qg = q0 + qr;
        Xb[(size_t)qg * 1024 + cl] = (bf16)(o0[g] * ri);
        Xb[(size_t)qg * 1024 + 32 + cl] = (bf16)(o1[g] * ri);
      }
    }
    __syncthreads();  // all exchanges done before next phase re-stages
  }
}

// ---------------------------------------------------------------------------
extern "C" void kernel_launch(void* const* d_in, const int* in_sizes, int n_in,
                              void* d_out, int out_size, void* d_ws,
                              size_t ws_size, hipStream_t stream) {
  const float* q = (const float*)d_in[0];
  const float* k = (const float*)d_in[1];
  const float* v = (const float*)d_in[2];
  const float* w_q = (const float*)d_in[4];
  const float* b_q = (const float*)d_in[5];
  const float* w_k = (const float*)d_in[6];
  const float* b_k = (const float*)d_in[7];
  const float* w_v = (const float*)d_in[8];
  const float* b_v = (const float*)d_in[9];
  const float* w_o = (const float*)d_in[10];
  const float* b_o = (const float*)d_in[11];

  bf16* ws = (bf16*)d_ws;
  const size_t NELEM = (size_t)4096 * 1024;
  bf16* Qp = ws;                // [B,H,S,DK]
  bf16* Kp = ws + NELEM;        // [B,H,S,DK]
  bf16* Vtp = ws + 2 * NELEM;   // [B,H,DK,S]
  bf16* Xp = ws + 3 * NELEM;    // [B,S,D] attn out
  bf16* Wt = ws + 4 * NELEM;    // 4 x [1024,1024] transposed bf16 weights
  bf16* Wto = Wt + 3145728;

  transpose_w<<<dim3(16, 16, 4), 256, 0, stream>>>(w_q, w_k, w_v, w_o, Wt);

  // fused Q/K/V projections (f32 inputs, fused convert): 768 blocks (3/CU)
  gemm_p<1, 4><<<dim3(8, 32, 3), 256, 0, stream>>>(
      q, k, v, nullptr, Wt, b_q, b_k, b_v, Qp, Kp, Vtp, nullptr);
  // attention: 512 blocks (2/CU), key-split waves + in-block pair balance
  attn_k<<<dim3(512), 256, 0, stream>>>(Qp, Kp, Vtp, Xp);
  // O projection: 64-row tiles -> 512 blocks (2/CU)
  gemm_p<0, 2><<<dim3(8, 64), 256, 0, stream>>>(
      nullptr, nullptr, nullptr, Xp, Wto, b_o, nullptr, nullptr, nullptr,
      nullptr, nullptr, (float*)d_out);
}

// Round 6
// 228.104 us; speedup vs baseline: 1.0849x; 1.0849x over previous
//
#include <hip/hip_runtime.h>
#include <hip/hip_bf16.h>

typedef __bf16 bf16;
typedef __bf16 bf16x2 __attribute__((ext_vector_type(2)));
typedef __bf16 bf16x8 __attribute__((ext_vector_type(8)));
typedef float f32x4 __attribute__((ext_vector_type(4)));
typedef float f32x16 __attribute__((ext_vector_type(16)));

#define MFMA16(a, b, c) __builtin_amdgcn_mfma_f32_16x16x32_bf16(a, b, c, 0, 0, 0)
#define MFMA32(a, b, c) __builtin_amdgcn_mfma_f32_32x32x16_bf16(a, b, c, 0, 0, 0)

// 0.125 (1/sqrt(DK)) * log2(e): folded into Q projection so attention uses exp2.
#define QSCALE 0.18033688f

// Async global->LDS, 16B per lane. Dest must be wave-uniform base (+lane*16).
__device__ __forceinline__ void gld16(const bf16* g, bf16* l) {
  __builtin_amdgcn_global_load_lds(
      (const __attribute__((address_space(1))) void*)g,
      (__attribute__((address_space(3))) void*)l, 16, 0, 0);
}

// ---------------------------------------------------------------------------
// prep_k: fused weight transpose+convert AND q/k/v f32->bf16 convert.
// grid (16,16,7), block 256.
//   z<4 : transpose+convert weight z: Wt[n][k] = W[k][n] (bf16).
//   z>=4: convert input (q,k,v)[z-4] to bf16, 16 MB each, grid-strided.
// ---------------------------------------------------------------------------
__global__ __launch_bounds__(256) void prep_k(
    const float* __restrict__ w0, const float* __restrict__ w1,
    const float* __restrict__ w2, const float* __restrict__ w3,
    bf16* __restrict__ dst, const float* __restrict__ q,
    const float* __restrict__ k, const float* __restrict__ v,
    bf16* __restrict__ qb, bf16* __restrict__ kb, bf16* __restrict__ vb) {
  const int t = threadIdx.x;
  if (blockIdx.z >= 4) {
    const int zi = blockIdx.z - 4;
    const float* src = zi == 0 ? q : zi == 1 ? k : v;
    bf16* d = zi == 0 ? qb : zi == 1 ? kb : vb;
    const int fb = blockIdx.y * 16 + blockIdx.x;  // 0..255
#pragma unroll
    for (int j = 0; j < 8; ++j) {
      const size_t i = ((size_t)j * 65536 + fb * 256 + t) * 8;
      float4 a = *(const float4*)(src + i);
      float4 b = *(const float4*)(src + i + 4);
      bf16x8 o;
      o[0] = (bf16)a.x; o[1] = (bf16)a.y; o[2] = (bf16)a.z; o[3] = (bf16)a.w;
      o[4] = (bf16)b.x; o[5] = (bf16)b.y; o[6] = (bf16)b.z; o[7] = (bf16)b.w;
      *(bf16x8*)(d + i) = o;
    }
    return;
  }

  __shared__ bf16 T[64][68];
  const float* W = blockIdx.z == 0 ? w0 : blockIdx.z == 1 ? w1
                   : blockIdx.z == 2 ? w2 : w3;
  bf16* Y = dst + (size_t)blockIdx.z * 1024 * 1024;
  const int r = t >> 2, c4 = t & 3;
  const int k0 = blockIdx.y * 64, n0 = blockIdx.x * 64;

  const float4* src = (const float4*)(W + (size_t)(k0 + r) * 1024 + n0 + c4 * 16);
  float4 f0 = src[0], f1 = src[1], f2 = src[2], f3 = src[3];
  bf16* row = &T[r][c4 * 16];
  row[0] = (bf16)f0.x; row[1] = (bf16)f0.y; row[2] = (bf16)f0.z; row[3] = (bf16)f0.w;
  row[4] = (bf16)f1.x; row[5] = (bf16)f1.y; row[6] = (bf16)f1.z; row[7] = (bf16)f1.w;
  row[8] = (bf16)f2.x; row[9] = (bf16)f2.y; row[10] = (bf16)f2.z; row[11] = (bf16)f2.w;
  row[12] = (bf16)f3.x; row[13] = (bf16)f3.y; row[14] = (bf16)f3.z; row[15] = (bf16)f3.w;
  __syncthreads();

  bf16x8 o0, o1;
#pragma unroll
  for (int j = 0; j < 8; ++j) o0[j] = T[c4 * 16 + j][r];
#pragma unroll
  for (int j = 0; j < 8; ++j) o1[j] = T[c4 * 16 + 8 + j][r];
  bf16* d = Y + (size_t)(n0 + r) * 1024 + k0 + c4 * 16;
  *(bf16x8*)d = o0;
  *(bf16x8*)(d + 8) = o1;
}

// ---------------------------------------------------------------------------
// GEMM v2 (round-4-verified): (MT*32)x128 tile, BK=64, m97-style
// global_load_lds staging for BOTH operands (bf16 inputs).
// LDS layout LINEAR [rows][64] bf16 (128 B/row) with XOR chunk swizzle:
//   16B chunk c of row r lives at byte r*128 + 16*(c ^ (r&7)).
// Realized per rule-21: linear DMA dest + inverse-swizzled GLOBAL source
// (lane at dest-chunk c' of row r loads global chunk c'^r) + same XOR on
// ds_read_b128 fragment reads -> bank-uniform.
// Two barriers per K-step; compiler auto-drains vmcnt before s_barrier.
// QKV=1 (MT=4): fused Q/K/V projection, z selects operands.
//   z=0: Q -> Qp [B,H,S,DK] scaled; z=1: K -> Kp; z=2: V -> Vtp [B,H,DK,S]
//   via in-LDS transpose (Tt spans SH; same-type aliasing, barrier-fenced).
// QKV=0 (MT=2): O projection -> Yf row-major f32.
// ---------------------------------------------------------------------------
template <int QKV, int MT>
__global__ __launch_bounds__(256, 3) void gemm_p(
    const bf16* __restrict__ xq, const bf16* __restrict__ xk,
    const bf16* __restrict__ xv, const bf16* __restrict__ Wt,
    const float* __restrict__ bq, const float* __restrict__ bk,
    const float* __restrict__ bv, bf16* __restrict__ Qp,
    bf16* __restrict__ Kp, bf16* __restrict__ Vtp, float* __restrict__ Yf) {
  constexpr int AROWS = MT * 32;
  __shared__ __align__(16) bf16 SH[AROWS * 64 + 128 * 64];
  bf16* Al = SH;
  bf16* Bl = SH + AROWS * 64;

  const int z = QKV ? blockIdx.z : 0;
  const bf16* X = QKV ? (z == 0 ? xq : z == 1 ? xk : xv) : xq;
  const bf16* Bt = Wt + (size_t)z * 1048576;
  const float* bias = QKV ? (z == 0 ? bq : z == 1 ? bk : bv) : bq;
  const float escale = (QKV && z == 0) ? QSCALE : 1.0f;

  const int t = threadIdx.x;
  const int wave = t >> 6, lane = t & 63, quad = lane >> 4, l16 = lane & 15;
  const int wm = (wave >> 1) * (MT * 16), wn = (wave & 1) * 64;
  const int bm = blockIdx.y * AROWS, bn = blockIdx.x * 128;

  // staging: lane -> (row-in-chunk r, dest chunk c'); global chunk = c'^r
  const int lr = (lane >> 3) & 7, lc = lane & 7;
  constexpr int NAC = AROWS / 32;  // A chunks per wave (4 or 2)
  const bf16* gA[NAC];
  bf16* lA[NAC];
#pragma unroll
  for (int i = 0; i < NAC; ++i) {
    const int q = wave * NAC + i;  // 1KB chunk = 8 rows
    gA[i] = X + (size_t)(bm + 8 * q + lr) * 1024 + 8 * (lc ^ lr);
    lA[i] = Al + q * 512;
  }
  const bf16* gB[4];
  bf16* lB[4];
#pragma unroll
  for (int i = 0; i < 4; ++i) {
    const int q = wave * 4 + i;
    gB[i] = Bt + (size_t)(bn + 8 * q + lr) * 1024 + 8 * (lc ^ lr);
    lB[i] = Bl + q * 512;
  }

  f32x4 acc[MT][4] = {};
  const int fswz = (l16 & 7) << 4;

  for (int kb = 0; kb < 1024; kb += 64) {
    __syncthreads();  // all waves done reading previous tile
#pragma unroll
    for (int i = 0; i < NAC; ++i) gld16(gA[i] + kb, lA[i]);
#pragma unroll
    for (int i = 0; i < 4; ++i) gld16(gB[i] + kb, lB[i]);
    __syncthreads();  // vmcnt(0) drain inserted by compiler before barrier

#pragma unroll
    for (int kk = 0; kk < 2; ++kk) {
      const int cb = (kk * 64 + quad * 16) ^ fswz;
      bf16x8 af[MT], bfr[4];
#pragma unroll
      for (int mt = 0; mt < MT; ++mt)
        af[mt] = *(const bf16x8*)((const char*)Al +
                                  (wm + mt * 16 + l16) * 128 + cb);
#pragma unroll
      for (int nt = 0; nt < 4; ++nt)
        bfr[nt] = *(const bf16x8*)((const char*)Bl +
                                   (wn + nt * 16 + l16) * 128 + cb);
#pragma unroll
      for (int mt = 0; mt < MT; ++mt)
#pragma unroll
        for (int nt = 0; nt < 4; ++nt)
          acc[mt][nt] = MFMA16(af[mt], bfr[nt], acc[mt][nt]);
    }
  }

  if (QKV && z == 2) {
    // ---- V^T epilogue: in-LDS transpose (Tt spans SH), coalesced stores
    bf16* Tt = SH;  // 64*136 = 8704 elems <= 16384
    const int b = bm >> 11;
    __syncthreads();  // everyone done with Al/Bl before reuse
#pragma unroll
    for (int half = 0; half < 2; ++half) {
      if ((wave & 1) == half) {
#pragma unroll
        for (int nt = 0; nt < 4; ++nt) {
          const int ln = nt * 16 + l16;
          const float bia = bias[bn + half * 64 + ln];
#pragma unroll
          for (int mt = 0; mt < 4; ++mt)
#pragma unroll
            for (int r = 0; r < 4; ++r) {
              const int m = wm + mt * 16 + quad * 4 + r;
              Tt[ln * 136 + m] = (bf16)(acc[mt][nt][r] + bia);
            }
        }
      }
      __syncthreads();
      {
        const int ln = t >> 2, seg = (t & 3) * 32;
        const int gn = bn + half * 64 + ln;
        const int h = gn >> 6, dk = gn & 63;
        const int s0 = (bm & 2047) + seg;
        bf16* dstp = Vtp + ((size_t)(b * 16 + h) * 64 + dk) * 2048 + s0;
        const bf16* srcp = Tt + ln * 136 + seg;
#pragma unroll
        for (int j = 0; j < 4; ++j)
          *(bf16x8*)(dstp + j * 8) = *(const bf16x8*)(srcp + j * 8);
      }
      __syncthreads();
    }
  } else {
    // ---- regular epilogue. C/D layout: row = quad*4 + r, col = l16 ----
#pragma unroll
    for (int mt = 0; mt < MT; ++mt)
#pragma unroll
      for (int nt = 0; nt < 4; ++nt) {
        const int gn = bn + wn + nt * 16 + l16;
        const float bia = bias[gn];
#pragma unroll
        for (int r = 0; r < 4; ++r) {
          const int gm = bm + wm + mt * 16 + quad * 4 + r;
          const float val = (acc[mt][nt][r] + bia) * escale;
          if (!QKV) {
            Yf[(size_t)gm * 1024 + gn] = val;
          } else {
            const int b = gm >> 11, s = gm & 2047;  // S = 2048
            const int h = gn >> 6, dk = gn & 63;    // DK = 64
            bf16* Y = (z == 0) ? Qp : Kp;
            Y[((size_t)(b * 16 + h) * 2048 + s) * 64 + dk] = (bf16)val;
          }
        }
      }
  }
}

// ---------------------------------------------------------------------------
// Flash attention v3c: round-3-verified structure + SAFE skipHi.
// Block = 4 waves (qsub = w&1 -> 32 q-rows, kpart = w>>1 -> even/odd
// 64-key tiles); two phases {x, 31-x}; exact-linear combine via LDS.
// skipHi: on the qsub=0 diagonal tile (k0 == q0, wave-uniform) the upper
// 32 keys are fully causal-masked -> skip hi QK/softmax/shfl/PV. All
// hi-half values (pkHi/pfHi) are declared AND used only inside the guard
// (no uninitialized-local surface, unlike round 2).
// ---------------------------------------------------------------------------
__global__ __launch_bounds__(256, 2) void attn_k(const bf16* __restrict__ Q,
                                                 const bf16* __restrict__ K,
                                                 const bf16* __restrict__ Vt,
                                                 bf16* __restrict__ X) {
  __shared__ __align__(16) char LB[65536];  // KB[4][8KB] | VB[4][8KB]
  __shared__ float Ex[2048];   // 8 KB o-exchange (one f32x16 round at a time)
  __shared__ float ExR[128];   // rs exchange
  __shared__ float rsL[4][32];

  bf16* KB = (bf16*)LB;            // 4 K tiles (2 parity x 2 kpart)
  bf16* VB = (bf16*)(LB + 32768);  // 4 V tiles

  const int t = threadIdx.x;
  const int wave = t >> 6, lane = t & 63;
  const int cl = lane & 31, h = lane >> 5;
  const int qsub = wave & 1, kpart = wave >> 1;

  const int n = blockIdx.x;
  const int xcd = n & 7, mm = n >> 3;
  const int bh = xcd + 8 * (mm & 3);
  const int pairx = mm >> 2;
  const int b = bh >> 4, hh = bh & 15;

  const bf16* Qb = Q + (size_t)bh * 2048 * 64;
  const bf16* Kb = K + (size_t)bh * 2048 * 64;
  const bf16* Vb = Vt + (size_t)bh * 64 * 2048;

  // staging role: thread t covers row sr, two swizzled 16B chunks
  const int sr = t >> 2, sc4 = t & 3;
  const int swz = (sr & 7) << 4;
  const int d0 = sr * 128 + ((sc4 * 32) ^ swz);
  const int d1 = sr * 128 + ((sc4 * 32 + 16) ^ swz);
  const int fswz = (cl & 7) << 4;  // frag-read swizzle (rows cl, cl+32)

  for (int ph = 0; ph < 2; ++ph) {
    const int qt = ph ? 31 - pairx : pairx;
    const int ntiles = qt + 1;
    const int S = (ntiles + 1) >> 1;  // supersteps (2 tiles each)
    const int q0 = qt * 64 + qsub * 32;

    // Q B-fragments (col = q = cl, k = d), kept in registers for the phase.
    bf16x8 qf[4];
#pragma unroll
    for (int ks = 0; ks < 4; ++ks)
      qf[ks] = *(const bf16x8*)(Qb + (size_t)(q0 + cl) * 64 + ks * 16 + h * 8);

    f32x16 o0 = {}, o1 = {};
    float rs = 0.f;

    // prologue: stage tiles {0,1} into parity-0 slots
#pragma unroll
    for (int p = 0; p < 2; ++p) {
      const bf16* gk = Kb + (size_t)(p * 64 + sr) * 64 + sc4 * 16;
      const bf16* gv = Vb + (size_t)sr * 2048 + p * 64 + sc4 * 16;
      bf16x8 ka = *(const bf16x8*)gk, kb2 = *(const bf16x8*)(gk + 8);
      bf16x8 va = *(const bf16x8*)gv, vb2 = *(const bf16x8*)(gv + 8);
      char* Kd = (char*)(KB + p * 4096);
      char* Vd = (char*)(VB + p * 4096);
      *(bf16x8*)(Kd + d0) = ka;  *(bf16x8*)(Kd + d1) = kb2;
      *(bf16x8*)(Vd + d0) = va;  *(bf16x8*)(Vd + d1) = vb2;
    }
    __syncthreads();

    for (int ss = 0; ss < S; ++ss) {
      const int par = ss & 1;
      const bool more = (ss + 1) < S;
      bf16x8 rk[2][2], rv[2][2];
      if (more) {  // prefetch both next-superstep tiles into registers
#pragma unroll
        for (int p = 0; p < 2; ++p) {
          const int kt2 = 2 * (ss + 1) + p;
          const bf16* gk = Kb + (size_t)kt2 * 4096 + sr * 64 + sc4 * 16;
          const bf16* gv = Vb + (size_t)sr * 2048 + kt2 * 64 + sc4 * 16;
          rk[p][0] = *(const bf16x8*)gk;
          rk[p][1] = *(const bf16x8*)(gk + 8);
          rv[p][0] = *(const bf16x8*)gv;
          rv[p][1] = *(const bf16x8*)(gv + 8);
        }
      }

      const int kt = 2 * ss + kpart;
      if (kt < ntiles) {
        const int k0 = kt * 64;
        const char* Kc = (const char*)(KB + (par * 2 + kpart) * 4096);
        const char* Vc = (const char*)(VB + (par * 2 + kpart) * 4096);
        const bool interior = (k0 + 63) <= q0;  // wave-uniform
        const bool skipHi = (k0 == q0);         // wave-uniform (qsub=0 diag)

        // ---- QK^T (swapped): S^T[key][q]; hi half only if needed
        f32x16 s0v = {}, s1v = {};
#pragma unroll
        for (int ks = 0; ks < 4; ++ks) {
          const int cb = ks * 32 + h * 16;
          bf16x8 f0 = *(const bf16x8*)(Kc + cl * 128 + (cb ^ fswz));
          s0v = MFMA32(f0, qf[ks], s0v);
        }
        if (!skipHi) {
#pragma unroll
          for (int ks = 0; ks < 4; ++ks) {
            const int cb = ks * 32 + h * 16;
            bf16x8 f1 = *(const bf16x8*)(Kc + (cl + 32) * 128 + (cb ^ fswz));
            s1v = MFMA32(f1, qf[ks], s1v);
          }
        }

        // ---- softmax in registers: exp2, causal mask, row-sum, pack bf16
        float ts = 0.f;
        auto smax = [&](const f32x16& sv, int mk, unsigned (&out)[4][2]) {
#pragma unroll
          for (int sl = 0; sl < 4; ++sl)
#pragma unroll
            for (int p = 0; p < 2; ++p) {
              float e0 = exp2f(sv[sl * 4 + 2 * p]);
              float e1 = exp2f(sv[sl * 4 + 2 * p + 1]);
              if (!interior) {
                const int ky = k0 + mk * 32 + 8 * sl + 4 * h + 2 * p;
                const int qg = q0 + cl;
                if (ky > qg) e0 = 0.f;
                if (ky + 1 > qg) e1 = 0.f;
              }
              ts += e0 + e1;
              union { bf16x2 v; unsigned u; } cv;
              cv.v[0] = (bf16)e0;
              cv.v[1] = (bf16)e1;
              out[sl][p] = cv.u;
            }
        };

        unsigned pkLo[4][2];
        smax(s0v, 0, pkLo);

        // ---- P -> A-frags (shfl form), lo half
        auto mkpf = [&](const unsigned (&pk)[4][2], int ks2) -> bf16x8 {
          const unsigned oe0 = pk[2 * ks2][0], oe1 = pk[2 * ks2][1];
          const unsigned oo0 = pk[2 * ks2 + 1][0], oo1 = pk[2 * ks2 + 1][1];
          const unsigned pe0 = (unsigned)__shfl_xor((int)oe0, 32, 64);
          const unsigned pe1 = (unsigned)__shfl_xor((int)oe1, 32, 64);
          const unsigned po0 = (unsigned)__shfl_xor((int)oo0, 32, 64);
          const unsigned po1 = (unsigned)__shfl_xor((int)oo1, 32, 64);
          union { unsigned u[4]; bf16x8 v; } fu;
          fu.u[0] = h ? po0 : oe0;
          fu.u[1] = h ? po1 : oe1;
          fu.u[2] = h ? oo0 : pe0;
          fu.u[3] = h ? oo1 : pe1;
          return fu.v;
        };
        bf16x8 pfLo[2];
        pfLo[0] = mkpf(pkLo, 0);
        pfLo[1] = mkpf(pkLo, 1);

        // ---- PV lo: keys k0..k0+31 (ks = 0,1)
#pragma unroll
        for (int ks = 0; ks < 2; ++ks) {
          const int cb = ks * 32 + h * 16;
          bf16x8 v0f = *(const bf16x8*)(Vc + cl * 128 + (cb ^ fswz));
          bf16x8 v1f = *(const bf16x8*)(Vc + (cl + 32) * 128 + (cb ^ fswz));
          o0 = MFMA32(pfLo[ks], v0f, o0);
          o1 = MFMA32(pfLo[ks], v1f, o1);
        }

        if (!skipHi) {  // hi half: keys k0+32..k0+63 (ks = 2,3)
          unsigned pkHi[4][2];
          smax(s1v, 1, pkHi);
          bf16x8 pfHi[2];
          pfHi[0] = mkpf(pkHi, 0);
          pfHi[1] = mkpf(pkHi, 1);
#pragma unroll
          for (int ks = 2; ks < 4; ++ks) {
            const int cb = ks * 32 + h * 16;
            bf16x8 v0f = *(const bf16x8*)(Vc + cl * 128 + (cb ^ fswz));
            bf16x8 v1f = *(const bf16x8*)(Vc + (cl + 32) * 128 + (cb ^ fswz));
            o0 = MFMA32(pfHi[ks - 2], v0f, o0);
            o1 = MFMA32(pfHi[ks - 2], v1f, o1);
          }
        }
        rs += ts;
      }

      if (more) {  // write prefetched tiles into the other parity slots
#pragma unroll
        for (int p = 0; p < 2; ++p) {
          char* Kd = (char*)(KB + ((par ^ 1) * 2 + p) * 4096);
          char* Vd = (char*)(VB + ((par ^ 1) * 2 + p) * 4096);
          *(bf16x8*)(Kd + d0) = rk[p][0];
          *(bf16x8*)(Kd + d1) = rk[p][1];
          *(bf16x8*)(Vd + d0) = rv[p][0];
          *(bf16x8*)(Vd + d1) = rv[p][1];
        }
      }
      __syncthreads();
    }

    // ---- combine partials across key partitions (exact: linear softmax)
    // Round A: o0 + rs
    if (kpart == 0) {
      float* e = Ex + qsub * 1024;
#pragma unroll
      for (int i = 0; i < 16; ++i) e[i * 64 + lane] = o0[i];
      ExR[qsub * 64 + lane] = rs;
    }
    __syncthreads();
    if (kpart == 1) {
      const float* e = Ex + qsub * 1024;
#pragma unroll
      for (int i = 0; i < 16; ++i) o0[i] += e[i * 64 + lane];
      rs += ExR[qsub * 64 + lane];
    }
    __syncthreads();
    // Round B: o1
    if (kpart == 0) {
      float* e = Ex + qsub * 1024;
#pragma unroll
      for (int i = 0; i < 16; ++i) e[i * 64 + lane] = o1[i];
    }
    __syncthreads();
    if (kpart == 1) {
      const float* e = Ex + qsub * 1024;
#pragma unroll
      for (int i = 0; i < 16; ++i) o1[i] += e[i * 64 + lane];

      // ---- epilogue: rinv broadcast via per-wave LDS, normalize, store
      const float rtot = rs + __shfl_xor(rs, 32, 64);
      rsL[wave][cl] = 1.0f / rtot;  // lanes h=0/1 write identical value
      __builtin_amdgcn_s_waitcnt(0xC07F);  // lgkmcnt(0): wave-local table
      bf16* Xb = X + (size_t)b * 2048 * 1024 + hh * 64;
#pragma unroll
      for (int g = 0; g < 16; ++g) {
        const int qr = (g & 3) + 8 * (g >> 2) + 4 * h;
        const float ri = rsL[wave][qr];
        const int qg = q0 + qr;
        Xb[(size_t)qg * 1024 + cl] = (bf16)(o0[g] * ri);
        Xb[(size_t)qg * 1024 + 32 + cl] = (bf16)(o1[g] * ri);
      }
    }
    __syncthreads();  // all exchanges done before next phase re-stages
  }
}

// ---------------------------------------------------------------------------
extern "C" void kernel_launch(void* const* d_in, const int* in_sizes, int n_in,
                              void* d_out, int out_size, void* d_ws,
                              size_t ws_size, hipStream_t stream) {
  const float* q = (const float*)d_in[0];
  const float* k = (const float*)d_in[1];
  const float* v = (const float*)d_in[2];
  const float* w_q = (const float*)d_in[4];
  const float* b_q = (const float*)d_in[5];
  const float* w_k = (const float*)d_in[6];
  const float* b_k = (const float*)d_in[7];
  const float* w_v = (const float*)d_in[8];
  const float* b_v = (const float*)d_in[9];
  const float* w_o = (const float*)d_in[10];
  const float* b_o = (const float*)d_in[11];

  bf16* ws = (bf16*)d_ws;
  const size_t NELEM = (size_t)4096 * 1024;
  bf16* Qp = ws;                // [B,H,S,DK]
  bf16* Kp = ws + NELEM;        // [B,H,S,DK]
  bf16* Vtp = ws + 2 * NELEM;   // [B,H,DK,S]
  bf16* Xp = ws + 3 * NELEM;    // [B,S,D] attn out; doubles as qb before attn
  bf16* Wt = ws + 4 * NELEM;    // 4 x [1024,1024] transposed bf16 weights
  bf16* Wto = Wt + 3145728;
  bf16* qb = Xp;
  bf16* kb = (bf16*)d_out;      // d_out scratch, overwritten by final GEMM
  bf16* vb = kb + NELEM;

  // fused prep: weight transpose (z 0-3) + q/k/v convert (z 4-6)
  prep_k<<<dim3(16, 16, 7), 256, 0, stream>>>(w_q, w_k, w_v, w_o, Wt, q, k, v,
                                              qb, kb, vb);

  // fused Q/K/V projections: 8x32x3 = 768 blocks (3/CU)
  gemm_p<1, 4><<<dim3(8, 32, 3), 256, 0, stream>>>(
      qb, kb, vb, Wt, b_q, b_k, b_v, Qp, Kp, Vtp, nullptr);
  // attention: 512 blocks (2/CU), key-split waves + in-block pair balance
  attn_k<<<dim3(512), 256, 0, stream>>>(Qp, Kp, Vtp, Xp);
  // O projection: 64-row tiles -> 512 blocks (2/CU)
  gemm_p<0, 2><<<dim3(8, 64), 256, 0, stream>>>(
      Xp, nullptr, nullptr, Wto, b_o, nullptr, nullptr, nullptr, nullptr,
      nullptr, (float*)d_out);
}

// Round 7
// 225.767 us; speedup vs baseline: 1.0961x; 1.0103x over previous
//
#include <hip/hip_runtime.h>
#include <hip/hip_bf16.h>

typedef __bf16 bf16;
typedef __bf16 bf16x2 __attribute__((ext_vector_type(2)));
typedef __bf16 bf16x8 __attribute__((ext_vector_type(8)));
typedef float f32x4 __attribute__((ext_vector_type(4)));
typedef float f32x16 __attribute__((ext_vector_type(16)));

#define MFMA16(a, b, c) __builtin_amdgcn_mfma_f32_16x16x32_bf16(a, b, c, 0, 0, 0)
#define MFMA32(a, b, c) __builtin_amdgcn_mfma_f32_32x32x16_bf16(a, b, c, 0, 0, 0)

// 0.125 (1/sqrt(DK)) * log2(e): folded into Q projection so attention uses exp2.
#define QSCALE 0.18033688f

// Async global->LDS, 16B per lane. Dest must be wave-uniform base (+lane*16).
__device__ __forceinline__ void gld16(const bf16* g, bf16* l) {
  __builtin_amdgcn_global_load_lds(
      (const __attribute__((address_space(1))) void*)g,
      (__attribute__((address_space(3))) void*)l, 16, 0, 0);
}

// ---------------------------------------------------------------------------
// prep_k: fused weight transpose+convert AND q/k/v f32->bf16 convert.
// grid (16,16,7), block 256.
//   z<4 : transpose+convert weight z: Wt[n][k] = W[k][n] (bf16).
//   z>=4: convert input (q,k,v)[z-4] to bf16, 16 MB each.
// ---------------------------------------------------------------------------
__global__ __launch_bounds__(256) void prep_k(
    const float* __restrict__ w0, const float* __restrict__ w1,
    const float* __restrict__ w2, const float* __restrict__ w3,
    bf16* __restrict__ dst, const float* __restrict__ q,
    const float* __restrict__ k, const float* __restrict__ v,
    bf16* __restrict__ qb, bf16* __restrict__ kb, bf16* __restrict__ vb) {
  const int t = threadIdx.x;
  if (blockIdx.z >= 4) {
    const int zi = blockIdx.z - 4;
    const float* src = zi == 0 ? q : zi == 1 ? k : v;
    bf16* d = zi == 0 ? qb : zi == 1 ? kb : vb;
    const int fb = blockIdx.y * 16 + blockIdx.x;  // 0..255
#pragma unroll
    for (int j = 0; j < 8; ++j) {
      const size_t i = ((size_t)j * 65536 + fb * 256 + t) * 8;
      float4 a = *(const float4*)(src + i);
      float4 b = *(const float4*)(src + i + 4);
      bf16x8 o;
      o[0] = (bf16)a.x; o[1] = (bf16)a.y; o[2] = (bf16)a.z; o[3] = (bf16)a.w;
      o[4] = (bf16)b.x; o[5] = (bf16)b.y; o[6] = (bf16)b.z; o[7] = (bf16)b.w;
      *(bf16x8*)(d + i) = o;
    }
    return;
  }

  __shared__ bf16 T[64][68];
  const float* W = blockIdx.z == 0 ? w0 : blockIdx.z == 1 ? w1
                   : blockIdx.z == 2 ? w2 : w3;
  bf16* Y = dst + (size_t)blockIdx.z * 1024 * 1024;
  const int r = t >> 2, c4 = t & 3;
  const int k0 = blockIdx.y * 64, n0 = blockIdx.x * 64;

  const float4* src = (const float4*)(W + (size_t)(k0 + r) * 1024 + n0 + c4 * 16);
  float4 f0 = src[0], f1 = src[1], f2 = src[2], f3 = src[3];
  bf16* row = &T[r][c4 * 16];
  row[0] = (bf16)f0.x; row[1] = (bf16)f0.y; row[2] = (bf16)f0.z; row[3] = (bf16)f0.w;
  row[4] = (bf16)f1.x; row[5] = (bf16)f1.y; row[6] = (bf16)f1.z; row[7] = (bf16)f1.w;
  row[8] = (bf16)f2.x; row[9] = (bf16)f2.y; row[10] = (bf16)f2.z; row[11] = (bf16)f2.w;
  row[12] = (bf16)f3.x; row[13] = (bf16)f3.y; row[14] = (bf16)f3.z; row[15] = (bf16)f3.w;
  __syncthreads();

  bf16x8 o0, o1;
#pragma unroll
  for (int j = 0; j < 8; ++j) o0[j] = T[c4 * 16 + j][r];
#pragma unroll
  for (int j = 0; j < 8; ++j) o1[j] = T[c4 * 16 + 8 + j][r];
  bf16* d = Y + (size_t)(n0 + r) * 1024 + k0 + c4 * 16;
  *(bf16x8*)d = o0;
  *(bf16x8*)(d + 8) = o1;
}

// ---------------------------------------------------------------------------
// GEMM v2 (round-4-verified): (MT*32)x128 tile, BK=64, m97-style
// global_load_lds staging for BOTH operands (bf16 inputs).
// LDS layout LINEAR [rows][64] bf16 (128 B/row) with XOR chunk swizzle:
//   16B chunk c of row r lives at byte r*128 + 16*(c ^ (r&7)).
// Realized per rule-21: linear DMA dest + inverse-swizzled GLOBAL source
// (lane at dest-chunk c' of row r loads global chunk c'^r) + same XOR on
// ds_read_b128 fragment reads -> bank-uniform.
// Two barriers per K-step; compiler auto-drains vmcnt before s_barrier.
// QKV=1 (MT=4): fused Q/K/V projection, z selects operands.
//   z=0: Q -> Qp [B,H,S,DK] scaled; z=1: K -> Kp; z=2: V -> Vtp [B,H,DK,S]
//   via in-LDS transpose (Tt spans SH; same-type aliasing, barrier-fenced).
// QKV=0 (MT=2): O projection -> Yf row-major f32.
// ---------------------------------------------------------------------------
template <int QKV, int MT>
__global__ __launch_bounds__(256, 3) void gemm_p(
    const bf16* __restrict__ xq, const bf16* __restrict__ xk,
    const bf16* __restrict__ xv, const bf16* __restrict__ Wt,
    const float* __restrict__ bq, const float* __restrict__ bk,
    const float* __restrict__ bv, bf16* __restrict__ Qp,
    bf16* __restrict__ Kp, bf16* __restrict__ Vtp, float* __restrict__ Yf) {
  constexpr int AROWS = MT * 32;
  __shared__ __align__(16) bf16 SH[AROWS * 64 + 128 * 64];
  bf16* Al = SH;
  bf16* Bl = SH + AROWS * 64;

  const int z = QKV ? blockIdx.z : 0;
  const bf16* X = QKV ? (z == 0 ? xq : z == 1 ? xk : xv) : xq;
  const bf16* Bt = Wt + (size_t)z * 1048576;
  const float* bias = QKV ? (z == 0 ? bq : z == 1 ? bk : bv) : bq;
  const float escale = (QKV && z == 0) ? QSCALE : 1.0f;

  const int t = threadIdx.x;
  const int wave = t >> 6, lane = t & 63, quad = lane >> 4, l16 = lane & 15;
  const int wm = (wave >> 1) * (MT * 16), wn = (wave & 1) * 64;
  const int bm = blockIdx.y * AROWS, bn = blockIdx.x * 128;

  // staging: lane -> (row-in-chunk r, dest chunk c'); global chunk = c'^r
  const int lr = (lane >> 3) & 7, lc = lane & 7;
  constexpr int NAC = AROWS / 32;  // A chunks per wave (4 or 2)
  const bf16* gA[NAC];
  bf16* lA[NAC];
#pragma unroll
  for (int i = 0; i < NAC; ++i) {
    const int q = wave * NAC + i;  // 1KB chunk = 8 rows
    gA[i] = X + (size_t)(bm + 8 * q + lr) * 1024 + 8 * (lc ^ lr);
    lA[i] = Al + q * 512;
  }
  const bf16* gB[4];
  bf16* lB[4];
#pragma unroll
  for (int i = 0; i < 4; ++i) {
    const int q = wave * 4 + i;
    gB[i] = Bt + (size_t)(bn + 8 * q + lr) * 1024 + 8 * (lc ^ lr);
    lB[i] = Bl + q * 512;
  }

  f32x4 acc[MT][4] = {};
  const int fswz = (l16 & 7) << 4;

  for (int kb = 0; kb < 1024; kb += 64) {
    __syncthreads();  // all waves done reading previous tile
#pragma unroll
    for (int i = 0; i < NAC; ++i) gld16(gA[i] + kb, lA[i]);
#pragma unroll
    for (int i = 0; i < 4; ++i) gld16(gB[i] + kb, lB[i]);
    __syncthreads();  // vmcnt(0) drain inserted by compiler before barrier

#pragma unroll
    for (int kk = 0; kk < 2; ++kk) {
      const int cb = (kk * 64 + quad * 16) ^ fswz;
      bf16x8 af[MT], bfr[4];
#pragma unroll
      for (int mt = 0; mt < MT; ++mt)
        af[mt] = *(const bf16x8*)((const char*)Al +
                                  (wm + mt * 16 + l16) * 128 + cb);
#pragma unroll
      for (int nt = 0; nt < 4; ++nt)
        bfr[nt] = *(const bf16x8*)((const char*)Bl +
                                   (wn + nt * 16 + l16) * 128 + cb);
#pragma unroll
      for (int mt = 0; mt < MT; ++mt)
#pragma unroll
        for (int nt = 0; nt < 4; ++nt)
          acc[mt][nt] = MFMA16(af[mt], bfr[nt], acc[mt][nt]);
    }
  }

  if (QKV && z == 2) {
    // ---- V^T epilogue: in-LDS transpose (Tt spans SH), coalesced stores
    bf16* Tt = SH;  // 64*136 = 8704 elems <= 16384
    const int b = bm >> 11;
    __syncthreads();  // everyone done with Al/Bl before reuse
#pragma unroll
    for (int half = 0; half < 2; ++half) {
      if ((wave & 1) == half) {
#pragma unroll
        for (int nt = 0; nt < 4; ++nt) {
          const int ln = nt * 16 + l16;
          const float bia = bias[bn + half * 64 + ln];
#pragma unroll
          for (int mt = 0; mt < 4; ++mt)
#pragma unroll
            for (int r = 0; r < 4; ++r) {
              const int m = wm + mt * 16 + quad * 4 + r;
              Tt[ln * 136 + m] = (bf16)(acc[mt][nt][r] + bia);
            }
        }
      }
      __syncthreads();
      {
        const int ln = t >> 2, seg = (t & 3) * 32;
        const int gn = bn + half * 64 + ln;
        const int h = gn >> 6, dk = gn & 63;
        const int s0 = (bm & 2047) + seg;
        bf16* dstp = Vtp + ((size_t)(b * 16 + h) * 64 + dk) * 2048 + s0;
        const bf16* srcp = Tt + ln * 136 + seg;
#pragma unroll
        for (int j = 0; j < 4; ++j)
          *(bf16x8*)(dstp + j * 8) = *(const bf16x8*)(srcp + j * 8);
      }
      __syncthreads();
    }
  } else {
    // ---- regular epilogue. C/D layout: row = quad*4 + r, col = l16 ----
#pragma unroll
    for (int mt = 0; mt < MT; ++mt)
#pragma unroll
      for (int nt = 0; nt < 4; ++nt) {
        const int gn = bn + wn + nt * 16 + l16;
        const float bia = bias[gn];
#pragma unroll
        for (int r = 0; r < 4; ++r) {
          const int gm = bm + wm + mt * 16 + quad * 4 + r;
          const float val = (acc[mt][nt][r] + bia) * escale;
          if (!QKV) {
            Yf[(size_t)gm * 1024 + gn] = val;
          } else {
            const int b = gm >> 11, s = gm & 2047;  // S = 2048
            const int h = gn >> 6, dk = gn & 63;    // DK = 64
            bf16* Y = (z == 0) ? Qp : Kp;
            Y[((size_t)(b * 16 + h) * 2048 + s) * 64 + dk] = (bf16)val;
          }
        }
      }
  }
}

// ---------------------------------------------------------------------------
// Flash attention v3b (round-4-verified, reverted from v3c): causal,
// no-running-max, 32x32x16 MFMA, swapped QK^T, softmax in registers,
// P->A-frags via __shfl_xor. Straight-line tile body (NO skipHi): the 8 QK
// MFMAs / 16 exp2 / shuffles / 8 PV MFMAs issue in unbroken phases -- the
// mid-body branch of v3c cost 10 us of ILP (r6 post-mortem).
//
// Block = 4 waves (qsub = w&1 -> 32 q-rows, kpart = w>>1 -> even/odd
// 64-key tiles); two phases {x, 31-x}; exact-linear combine via LDS.
// Grid 512: n -> xcd=n&7, bh=xcd+8*(mm&3), pairx=mm>>2 (K/V L2-resident/XCD).
// Superstep s stages tiles {2s, 2s+1} (K and V) double-buffered: 64 KB LDS,
// XOR-swizzled 16B chunks (byte ^= (row&7)<<4) on both write and read.
// One __syncthreads per superstep. LDS total 73 KB -> 2 blocks/CU.
// ---------------------------------------------------------------------------
__global__ __launch_bounds__(256, 2) void attn_k(const bf16* __restrict__ Q,
                                                 const bf16* __restrict__ K,
                                                 const bf16* __restrict__ Vt,
                                                 bf16* __restrict__ X) {
  __shared__ __align__(16) char LB[65536];  // KB[4][8KB] | VB[4][8KB]
  __shared__ float Ex[2048];   // 8 KB o-exchange (one f32x16 round at a time)
  __shared__ float ExR[128];   // rs exchange
  __shared__ float rsL[4][32];

  bf16* KB = (bf16*)LB;            // 4 K tiles (2 parity x 2 kpart)
  bf16* VB = (bf16*)(LB + 32768);  // 4 V tiles

  const int t = threadIdx.x;
  const int wave = t >> 6, lane = t & 63;
  const int cl = lane & 31, h = lane >> 5;
  const int qsub = wave & 1, kpart = wave >> 1;

  const int n = blockIdx.x;
  const int xcd = n & 7, mm = n >> 3;
  const int bh = xcd + 8 * (mm & 3);
  const int pairx = mm >> 2;
  const int b = bh >> 4, hh = bh & 15;

  const bf16* Qb = Q + (size_t)bh * 2048 * 64;
  const bf16* Kb = K + (size_t)bh * 2048 * 64;
  const bf16* Vb = Vt + (size_t)bh * 64 * 2048;

  // staging role: thread t covers row sr, two swizzled 16B chunks
  const int sr = t >> 2, sc4 = t & 3;
  const int swz = (sr & 7) << 4;
  const int d0 = sr * 128 + ((sc4 * 32) ^ swz);
  const int d1 = sr * 128 + ((sc4 * 32 + 16) ^ swz);
  const int fswz = (cl & 7) << 4;  // frag-read swizzle (rows cl, cl+32)

  for (int ph = 0; ph < 2; ++ph) {
    const int qt = ph ? 31 - pairx : pairx;
    const int ntiles = qt + 1;
    const int S = (ntiles + 1) >> 1;  // supersteps (2 tiles each)
    const int q0 = qt * 64 + qsub * 32;

    // Q B-fragments (col = q = cl, k = d), kept in registers for the phase.
    bf16x8 qf[4];
#pragma unroll
    for (int ks = 0; ks < 4; ++ks)
      qf[ks] = *(const bf16x8*)(Qb + (size_t)(q0 + cl) * 64 + ks * 16 + h * 8);

    f32x16 o0 = {}, o1 = {};
    float rs = 0.f;

    // prologue: stage tiles {0,1} into parity-0 slots
#pragma unroll
    for (int p = 0; p < 2; ++p) {
      const bf16* gk = Kb + (size_t)(p * 64 + sr) * 64 + sc4 * 16;
      const bf16* gv = Vb + (size_t)sr * 2048 + p * 64 + sc4 * 16;
      bf16x8 ka = *(const bf16x8*)gk, kb2 = *(const bf16x8*)(gk + 8);
      bf16x8 va = *(const bf16x8*)gv, vb2 = *(const bf16x8*)(gv + 8);
      char* Kd = (char*)(KB + p * 4096);
      char* Vd = (char*)(VB + p * 4096);
      *(bf16x8*)(Kd + d0) = ka;  *(bf16x8*)(Kd + d1) = kb2;
      *(bf16x8*)(Vd + d0) = va;  *(bf16x8*)(Vd + d1) = vb2;
    }
    __syncthreads();

    for (int ss = 0; ss < S; ++ss) {
      const int par = ss & 1;
      const bool more = (ss + 1) < S;
      bf16x8 rk[2][2], rv[2][2];
      if (more) {  // prefetch both next-superstep tiles into registers
#pragma unroll
        for (int p = 0; p < 2; ++p) {
          const int kt2 = 2 * (ss + 1) + p;
          const bf16* gk = Kb + (size_t)kt2 * 4096 + sr * 64 + sc4 * 16;
          const bf16* gv = Vb + (size_t)sr * 2048 + kt2 * 64 + sc4 * 16;
          rk[p][0] = *(const bf16x8*)gk;
          rk[p][1] = *(const bf16x8*)(gk + 8);
          rv[p][0] = *(const bf16x8*)gv;
          rv[p][1] = *(const bf16x8*)(gv + 8);
        }
      }

      const int kt = 2 * ss + kpart;
      if (kt < ntiles) {
        const int k0 = kt * 64;
        const char* Kc = (const char*)(KB + (par * 2 + kpart) * 4096);
        const char* Vc = (const char*)(VB + (par * 2 + kpart) * 4096);
        const bool interior = (k0 + 63) <= q0;  // wave-uniform

        // ---- QK^T (swapped): S^T[key][q]
        f32x16 s0v = {}, s1v = {};
#pragma unroll
        for (int ks = 0; ks < 4; ++ks) {
          const int cb = ks * 32 + h * 16;
          bf16x8 f0 = *(const bf16x8*)(Kc + cl * 128 + (cb ^ fswz));
          bf16x8 f1 = *(const bf16x8*)(Kc + (cl + 32) * 128 + (cb ^ fswz));
          s0v = MFMA32(f0, qf[ks], s0v);
          s1v = MFMA32(f1, qf[ks], s1v);
        }

        // ---- softmax in registers: exp2, causal mask, row-sum, pack bf16
        unsigned pk[8][2];  // [s64 = key>>3][pair]
        float ts = 0.f;
        auto smax = [&](const f32x16& sv, int mk) {
#pragma unroll
          for (int sl = 0; sl < 4; ++sl)
#pragma unroll
            for (int p = 0; p < 2; ++p) {
              float e0 = exp2f(sv[sl * 4 + 2 * p]);
              float e1 = exp2f(sv[sl * 4 + 2 * p + 1]);
              if (!interior) {
                const int ky = k0 + mk * 32 + 8 * sl + 4 * h + 2 * p;
                const int qg = q0 + cl;
                if (ky > qg) e0 = 0.f;
                if (ky + 1 > qg) e1 = 0.f;
              }
              ts += e0 + e1;
              union { bf16x2 v; unsigned u; } cv;
              cv.v[0] = (bf16)e0;
              cv.v[1] = (bf16)e1;
              pk[mk * 4 + sl][p] = cv.u;
            }
        };
        smax(s0v, 0);
        smax(s1v, 1);
        rs += ts;

        // ---- P -> A-frags (round-1-verified shfl form):
        // lane (q=cl, h) frag ks elem j = P[q][16ks+8h+j]
        bf16x8 pf[4];
#pragma unroll
        for (int ks = 0; ks < 4; ++ks) {
          const unsigned oe0 = pk[2 * ks][0], oe1 = pk[2 * ks][1];
          const unsigned oo0 = pk[2 * ks + 1][0], oo1 = pk[2 * ks + 1][1];
          const unsigned pe0 = (unsigned)__shfl_xor((int)oe0, 32, 64);
          const unsigned pe1 = (unsigned)__shfl_xor((int)oe1, 32, 64);
          const unsigned po0 = (unsigned)__shfl_xor((int)oo0, 32, 64);
          const unsigned po1 = (unsigned)__shfl_xor((int)oo1, 32, 64);
          union { unsigned u[4]; bf16x8 v; } fu;
          fu.u[0] = h ? po0 : oe0;
          fu.u[1] = h ? po1 : oe1;
          fu.u[2] = h ? oo0 : pe0;
          fu.u[3] = h ? oo1 : pe1;
          pf[ks] = fu.v;
        }

        // ---- PV: O[q][d] += P[q][key] * V[key][d] (Vl rows = d)
#pragma unroll
        for (int ks = 0; ks < 4; ++ks) {
          const int cb = ks * 32 + h * 16;
          bf16x8 v0f = *(const bf16x8*)(Vc + cl * 128 + (cb ^ fswz));
          bf16x8 v1f = *(const bf16x8*)(Vc + (cl + 32) * 128 + (cb ^ fswz));
          o0 = MFMA32(pf[ks], v0f, o0);
          o1 = MFMA32(pf[ks], v1f, o1);
        }
      }

      if (more) {  // write prefetched tiles into the other parity slots
#pragma unroll
        for (int p = 0; p < 2; ++p) {
          char* Kd = (char*)(KB + ((par ^ 1) * 2 + p) * 4096);
          char* Vd = (char*)(VB + ((par ^ 1) * 2 + p) * 4096);
          *(bf16x8*)(Kd + d0) = rk[p][0];
          *(bf16x8*)(Kd + d1) = rk[p][1];
          *(bf16x8*)(Vd + d0) = rv[p][0];
          *(bf16x8*)(Vd + d1) = rv[p][1];
        }
      }
      __syncthreads();
    }

    // ---- combine partials across key partitions (exact: linear softmax)
    // Round A: o0 + rs
    if (kpart == 0) {
      float* e = Ex + qsub * 1024;
#pragma unroll
      for (int i = 0; i < 16; ++i) e[i * 64 + lane] = o0[i];
      ExR[qsub * 64 + lane] = rs;
    }
    __syncthreads();
    if (kpart == 1) {
      const float* e = Ex + qsub * 1024;
#pragma unroll
      for (int i = 0; i < 16; ++i) o0[i] += e[i * 64 + lane];
      rs += ExR[qsub * 64 + lane];
    }
    __syncthreads();
    // Round B: o1
    if (kpart == 0) {
      float* e = Ex + qsub * 1024;
#pragma unroll
      for (int i = 0; i < 16; ++i) e[i * 64 + lane] = o1[i];
    }
    __syncthreads();
    if (kpart == 1) {
      const float* e = Ex + qsub * 1024;
#pragma unroll
      for (int i = 0; i < 16; ++i) o1[i] += e[i * 64 + lane];

      // ---- epilogue: rinv broadcast via per-wave LDS, normalize, store
      const float rtot = rs + __shfl_xor(rs, 32, 64);
      rsL[wave][cl] = 1.0f / rtot;  // lanes h=0/1 write identical value
      __builtin_amdgcn_s_waitcnt(0xC07F);  // lgkmcnt(0): wave-local table
      bf16* Xb = X + (size_t)b * 2048 * 1024 + hh * 64;
#pragma unroll
      for (int g = 0; g < 16; ++g) {
        const int qr = (g & 3) + 8 * (g >> 2) + 4 * h;
        const float ri = rsL[wave][qr];
        const int qg = q0 + qr;
        Xb[(size_t)qg * 1024 + cl] = (bf16)(o0[g] * ri);
        Xb[(size_t)qg * 1024 + 32 + cl] = (bf16)(o1[g] * ri);
      }
    }
    __syncthreads();  // all exchanges done before next phase re-stages
  }
}

// ---------------------------------------------------------------------------
extern "C" void kernel_launch(void* const* d_in, const int* in_sizes, int n_in,
                              void* d_out, int out_size, void* d_ws,
                              size_t ws_size, hipStream_t stream) {
  const float* q = (const float*)d_in[0];
  const float* k = (const float*)d_in[1];
  const float* v = (const float*)d_in[2];
  const float* w_q = (const float*)d_in[4];
  const float* b_q = (const float*)d_in[5];
  const float* w_k = (const float*)d_in[6];
  const float* b_k = (const float*)d_in[7];
  const float* w_v = (const float*)d_in[8];
  const float* b_v = (const float*)d_in[9];
  const float* w_o = (const float*)d_in[10];
  const float* b_o = (const float*)d_in[11];

  bf16* ws = (bf16*)d_ws;
  const size_t NELEM = (size_t)4096 * 1024;
  bf16* Qp = ws;                // [B,H,S,DK]
  bf16* Kp = ws + NELEM;        // [B,H,S,DK]
  bf16* Vtp = ws + 2 * NELEM;   // [B,H,DK,S]
  bf16* Xp = ws + 3 * NELEM;    // [B,S,D] attn out; doubles as qb before attn
  bf16* Wt = ws + 4 * NELEM;    // 4 x [1024,1024] transposed bf16 weights
  bf16* Wto = Wt + 3145728;
  bf16* qb = Xp;
  bf16* kb = (bf16*)d_out;      // d_out scratch, overwritten by final GEMM
  bf16* vb = kb + NELEM;

  // fused prep: weight transpose (z 0-3) + q/k/v convert (z 4-6)
  prep_k<<<dim3(16, 16, 7), 256, 0, stream>>>(w_q, w_k, w_v, w_o, Wt, q, k, v,
                                              qb, kb, vb);

  // fused Q/K/V projections: 8x32x3 = 768 blocks (3/CU)
  gemm_p<1, 4><<<dim3(8, 32, 3), 256, 0, stream>>>(
      qb, kb, vb, Wt, b_q, b_k, b_v, Qp, Kp, Vtp, nullptr);
  // attention: 512 blocks (2/CU), key-split waves + in-block pair balance
  attn_k<<<dim3(512), 256, 0, stream>>>(Qp, Kp, Vtp, Xp);
  // O projection: 64-row tiles -> 512 blocks (2/CU)
  gemm_p<0, 2><<<dim3(8, 64), 256, 0, stream>>>(
      Xp, nullptr, nullptr, Wto, b_o, nullptr, nullptr, nullptr, nullptr,
      nullptr, (float*)d_out);
}